// Round 1
// baseline (395.259 us; speedup 1.0000x reference)
//
#include <hip/hip_runtime.h>
#include <hip/hip_bf16.h>

typedef __bf16 bf16x8 __attribute__((ext_vector_type(8)));
typedef float f32x4 __attribute__((ext_vector_type(4)));
typedef unsigned int u32x4 __attribute__((ext_vector_type(4)));

#define MFMA16(a, b, c) __builtin_amdgcn_mfma_f32_16x16x32_bf16((a), (b), (c), 0, 0, 0)
#define DEVI static __device__ __forceinline__

DEVI unsigned short f2bf(float f) {  // round-to-nearest-even fp32 -> bf16
  union { float f; unsigned u; } x; x.f = f;
  unsigned r = x.u + 0x7fffu + ((x.u >> 16) & 1u);
  return (unsigned short)(r >> 16);
}
DEVI float bf2f(unsigned short h) {
  union { unsigned u; float f; } x; x.u = ((unsigned)h) << 16;
  return x.f;
}
DEVI bf16x8 ldg16(const unsigned short* p) {  // 16B aligned load -> bf16x8 frag
  u32x4 t = *reinterpret_cast<const u32x4*>(p);
  return __builtin_bit_cast(bf16x8, t);
}

// ---------- kernel 1: transpose + hi/lo split: x[512][4096] -> xThi/xTlo [4096][512]
__global__ __launch_bounds__(256) void xsplit_kernel(const float* __restrict__ x,
    unsigned short* __restrict__ xThi, unsigned short* __restrict__ xTlo) {
  __shared__ unsigned short hs[64][72];
  __shared__ unsigned short ls[64][72];
  const int c0 = blockIdx.x * 64, j0 = blockIdx.y * 64;
  const int t = threadIdx.x;
  {
    const int cr = t >> 2, jc = (t & 3) * 16;
    const float4* s4 = reinterpret_cast<const float4*>(x + (c0 + cr) * 4096 + j0 + jc);
#pragma unroll
    for (int q = 0; q < 4; ++q) {
      float4 v = s4[q];
      float vv[4] = {v.x, v.y, v.z, v.w};
#pragma unroll
      for (int e = 0; e < 4; ++e) {
        unsigned short h = f2bf(vv[e]);
        hs[cr][jc + q * 4 + e] = h;
        ls[cr][jc + q * 4 + e] = f2bf(vv[e] - bf2f(h));
      }
    }
  }
  __syncthreads();
  {
    const int jr = t >> 2, cc = (t & 3) * 16;
    unsigned short hb[16] __attribute__((aligned(16)));
    unsigned short lb[16] __attribute__((aligned(16)));
#pragma unroll
    for (int u = 0; u < 16; ++u) { hb[u] = hs[cc + u][jr]; lb[u] = ls[cc + u][jr]; }
    unsigned short* dh = xThi + (j0 + jr) * 512 + c0 + cc;
    unsigned short* dl = xTlo + (j0 + jr) * 512 + c0 + cc;
    reinterpret_cast<u32x4*>(dh)[0] = reinterpret_cast<const u32x4*>(hb)[0];
    reinterpret_cast<u32x4*>(dh)[1] = reinterpret_cast<const u32x4*>(hb)[1];
    reinterpret_cast<u32x4*>(dl)[0] = reinterpret_cast<const u32x4*>(lb)[0];
    reinterpret_cast<u32x4*>(dl)[1] = reinterpret_cast<const u32x4*>(lb)[1];
  }
}

// ---------- kernel 2: elementwise hi/lo split for weight matrices
__global__ __launch_bounds__(256) void wsplit_kernel(const float* __restrict__ in,
    unsigned short* __restrict__ hi, unsigned short* __restrict__ lo, int n4) {
  int i = blockIdx.x * 256 + threadIdx.x;
  if (i >= n4) return;
  float4 v = reinterpret_cast<const float4*>(in)[i];
  float vv[4] = {v.x, v.y, v.z, v.w};
  unsigned short hb[4] __attribute__((aligned(8)));
  unsigned short lb[4] __attribute__((aligned(8)));
#pragma unroll
  for (int e = 0; e < 4; ++e) { hb[e] = f2bf(vv[e]); lb[e] = f2bf(vv[e] - bf2f(hb[e])); }
  reinterpret_cast<uint2*>(hi)[i] = *reinterpret_cast<const uint2*>(hb);
  reinterpret_cast<uint2*>(lo)[i] = *reinterpret_cast<const uint2*>(lb);
}

// ---------- kernel 3: kx/qx projections (split-bf16 MFMA, fp32-accurate)
// D[d][j] = sum_c W[d][c] x[c][j]; stored transposed -> kxT/qxT [4096][64] hi+lo
__global__ __launch_bounds__(256) void kqproj_kernel(
    const unsigned short* __restrict__ Wkhi, const unsigned short* __restrict__ Wklo,
    const unsigned short* __restrict__ Wqhi, const unsigned short* __restrict__ Wqlo,
    const unsigned short* __restrict__ xThi, const unsigned short* __restrict__ xTlo,
    unsigned short* __restrict__ kxThi, unsigned short* __restrict__ kxTlo,
    unsigned short* __restrict__ qxThi, unsigned short* __restrict__ qxTlo) {
  const int mb = blockIdx.y;                       // 0..3 -> kx, 4..7 -> qx
  const int w = threadIdx.x >> 6, lane = threadIdx.x & 63;
  const int li = lane & 15, g = lane >> 4;
  const int j0 = blockIdx.x * 64 + w * 16;
  const unsigned short* Whi = (mb < 4 ? Wkhi : Wqhi) + ((mb & 3) * 16 + li) * 512 + g * 8;
  const unsigned short* Wlo = (mb < 4 ? Wklo : Wqlo) + ((mb & 3) * 16 + li) * 512 + g * 8;
  const unsigned short* Xh = xThi + (j0 + li) * 512 + g * 8;
  const unsigned short* Xl = xTlo + (j0 + li) * 512 + g * 8;
  f32x4 acc = f32x4{0.f, 0.f, 0.f, 0.f};
  for (int kf = 0; kf < 16; ++kf) {
    const int o = kf * 32;
    bf16x8 ah = ldg16(Whi + o), al = ldg16(Wlo + o);
    bf16x8 bh = ldg16(Xh + o), bl = ldg16(Xl + o);
    acc = MFMA16(ah, bh, acc);
    acc = MFMA16(ah, bl, acc);
    acc = MFMA16(al, bh, acc);
  }
  unsigned short hv[4] __attribute__((aligned(8))), lv[4] __attribute__((aligned(8)));
#pragma unroll
  for (int r = 0; r < 4; ++r) {
    hv[r] = f2bf(acc[r]);
    lv[r] = f2bf(acc[r] - bf2f(hv[r]));
  }
  unsigned short* oh = (mb < 4 ? kxThi : qxThi) + (j0 + li) * 64 + (mb & 3) * 16 + g * 4;
  unsigned short* ol = (mb < 4 ? kxTlo : qxTlo) + (j0 + li) * 64 + (mb & 3) * 16 + g * 4;
  *reinterpret_cast<uint2*>(oh) = *reinterpret_cast<const uint2*>(hv);
  *reinterpret_cast<uint2*>(ol) = *reinterpret_cast<const uint2*>(lv);
}

// ---------- kernel 4: vx projection, computed transposed: D[j][c] = sum_c' xT[j][c'] Wv[c][c']
// stored as vbf[c][j] ([512][4096] bf16) with contiguous 8B stores
__global__ __launch_bounds__(256) void vproj_kernel(
    const unsigned short* __restrict__ Wvhi, const unsigned short* __restrict__ Wvlo,
    const unsigned short* __restrict__ xThi, const unsigned short* __restrict__ xTlo,
    unsigned short* __restrict__ vbf) {
  const int jb = blockIdx.x, cb = blockIdx.y;
  const int w = threadIdx.x >> 6, lane = threadIdx.x & 63;
  const int li = lane & 15, g = lane >> 4;
  const int j0 = jb * 16;
  const int c0 = cb * 64 + w * 16;
  const unsigned short* Ah = xThi + (j0 + li) * 512 + g * 8;
  const unsigned short* Al = xTlo + (j0 + li) * 512 + g * 8;
  const unsigned short* Bh = Wvhi + (c0 + li) * 512 + g * 8;
  const unsigned short* Bl = Wvlo + (c0 + li) * 512 + g * 8;
  f32x4 acc = f32x4{0.f, 0.f, 0.f, 0.f};
  for (int kf = 0; kf < 16; ++kf) {
    const int o = kf * 32;
    bf16x8 ah = ldg16(Ah + o), al = ldg16(Al + o);
    bf16x8 bh = ldg16(Bh + o), bl = ldg16(Bl + o);
    acc = MFMA16(ah, bh, acc);
    acc = MFMA16(ah, bl, acc);
    acc = MFMA16(al, bh, acc);
  }
  unsigned short hv[4] __attribute__((aligned(8)));
#pragma unroll
  for (int r = 0; r < 4; ++r) hv[r] = f2bf(acc[r]);
  *reinterpret_cast<uint2*>(vbf + (c0 + li) * 4096 + j0 + g * 4) = *reinterpret_cast<const uint2*>(hv);
}

// ---------- kernel 5: fused flash attention (transposed: computes out^T fragments)
// block = 4 waves, 16 query rows (i). Wave w computes S^T quadrant j=[w*16,w*16+16),
// P shared via swizzled LDS; each wave accumulates PV for channels [w*128, w*128+128).
__global__ __launch_bounds__(256) void attn_kernel(
    const unsigned short* __restrict__ kxThi, const unsigned short* __restrict__ kxTlo,
    const unsigned short* __restrict__ qxThi, const unsigned short* __restrict__ qxTlo,
    const unsigned short* __restrict__ vbf, float* __restrict__ out) {
  __shared__ __align__(16) unsigned short Pl[1024];  // 16 x 64 bf16, XOR-swizzled
  __shared__ float smax[4][16];
  __shared__ float ssum[4][16];
  const int w = threadIdx.x >> 6, lane = threadIdx.x & 63;
  const int li = lane & 15, g = lane >> 4;
  const int i0 = blockIdx.x * 16;
  const float L2E = 1.4426950408889634f;

  // Q (= kx^T rows i0..i0+15) as B-operand fragments, hi/lo, kf=0,1
  bf16x8 qbh[2], qbl[2];
  {
    const unsigned short* ph = kxThi + (i0 + li) * 64 + g * 8;
    const unsigned short* pl = kxTlo + (i0 + li) * 64 + g * 8;
    qbh[0] = ldg16(ph); qbh[1] = ldg16(ph + 32);
    qbl[0] = ldg16(pl); qbl[1] = ldg16(pl + 32);
  }
  f32x4 acc[8];
#pragma unroll
  for (int cf = 0; cf < 8; ++cf) acc[cf] = f32x4{0.f, 0.f, 0.f, 0.f};
  float m_run = -3.0e38f, l_run = 0.f;
  char* plb = reinterpret_cast<char*>(Pl);

  for (int j0 = 0; j0 < 4096; j0 += 64) {
    // --- S^T quadrant: rows j = j0 + w*16 + (0..15), cols i (3-term split product)
    f32x4 s = f32x4{0.f, 0.f, 0.f, 0.f};
    {
      const unsigned short* ah_p = qxThi + (j0 + w * 16 + li) * 64 + g * 8;
      const unsigned short* al_p = qxTlo + (j0 + w * 16 + li) * 64 + g * 8;
#pragma unroll
      for (int kf = 0; kf < 2; ++kf) {
        bf16x8 ah = ldg16(ah_p + kf * 32);
        bf16x8 al = ldg16(al_p + kf * 32);
        s = MFMA16(ah, qbh[kf], s);
        s = MFMA16(ah, qbl[kf], s);
        s = MFMA16(al, qbh[kf], s);
      }
    }
    // --- quadrant max per column i (lane's column is li; rows j live in r and lane-group g)
    float pm = fmaxf(fmaxf(s[0], s[1]), fmaxf(s[2], s[3]));
    pm = fmaxf(pm, __shfl_xor(pm, 16));
    pm = fmaxf(pm, __shfl_xor(pm, 32));
    if (lane < 16) smax[w][li] = pm;
    __syncthreads();
    const float m_new = fmaxf(m_run,
        fmaxf(fmaxf(smax[0][li], smax[1][li]), fmaxf(smax[2][li], smax[3][li])));
    const float fac = exp2f((m_run - m_new) * L2E);
    float p[4];
#pragma unroll
    for (int r = 0; r < 4; ++r) p[r] = exp2f((s[r] - m_new) * L2E);
    float ps = (p[0] + p[1]) + (p[2] + p[3]);
    ps += __shfl_xor(ps, 16);
    ps += __shfl_xor(ps, 32);
    if (lane < 16) ssum[w][li] = ps;
    {  // write P[i=li][jt = w*16+g*4 .. +3] as 4 bf16 (8B), swizzled
      unsigned short pv[4] __attribute__((aligned(8)));
#pragma unroll
      for (int r = 0; r < 4; ++r) pv[r] = f2bf(p[r]);
      const int pb = (li * 128 + w * 32 + g * 8) ^ ((li & 7) << 4);
      *reinterpret_cast<uint2*>(plb + pb) = *reinterpret_cast<const uint2*>(pv);
    }
    __syncthreads();
    l_run = l_run * fac + ((ssum[0][li] + ssum[1][li]) + (ssum[2][li] + ssum[3][li]));
    m_run = m_new;
#pragma unroll
    for (int cf = 0; cf < 8; ++cf) {
#pragma unroll
      for (int r = 0; r < 4; ++r) acc[cf][r] *= fac;
    }
    // --- PV: B = P from LDS (2 frags), A = V rows (global, 16B contiguous, L2-resident)
    bf16x8 bp[2];
#pragma unroll
    for (int kf = 0; kf < 2; ++kf) {
      const int rb = (li * 128 + kf * 64 + g * 16) ^ ((li & 7) << 4);
      bp[kf] = __builtin_bit_cast(bf16x8, *reinterpret_cast<const u32x4*>(plb + rb));
    }
#pragma unroll
    for (int cf = 0; cf < 8; ++cf) {
      const unsigned short* vp = vbf + (w * 128 + cf * 16 + li) * 4096 + j0 + g * 8;
      acc[cf] = MFMA16(ldg16(vp), bp[0], acc[cf]);
      acc[cf] = MFMA16(ldg16(vp + 32), bp[1], acc[cf]);
    }
    __syncthreads();
  }
  const float inv_l = 1.0f / l_run;
#pragma unroll
  for (int cf = 0; cf < 8; ++cf) {
    float4 o;
    o.x = acc[cf][0] * inv_l; o.y = acc[cf][1] * inv_l;
    o.z = acc[cf][2] * inv_l; o.w = acc[cf][3] * inv_l;
    *reinterpret_cast<float4*>(out + (i0 + li) * 512 + w * 128 + cf * 16 + g * 4) = o;
  }
}

extern "C" void kernel_launch(void* const* d_in, const int* in_sizes, int n_in,
                              void* d_out, int out_size, void* d_ws, size_t ws_size,
                              hipStream_t stream) {
  const float* x  = (const float*)d_in[0];   // [512][4096]
  const float* Wk = (const float*)d_in[1];   // [64][512]
  const float* Wq = (const float*)d_in[2];   // [64][512]
  const float* Wv = (const float*)d_in[3];   // [512][512]
  float* out = (float*)d_out;                // [4096][512]
  char* ws = (char*)d_ws;
  size_t off = 0;
  auto alloc = [&](size_t bytes) { char* p = ws + off; off += bytes; return p; };
  unsigned short* xThi  = (unsigned short*)alloc(4096ull * 512 * 2);
  unsigned short* xTlo  = (unsigned short*)alloc(4096ull * 512 * 2);
  unsigned short* Wkhi  = (unsigned short*)alloc(64 * 512 * 2);
  unsigned short* Wklo  = (unsigned short*)alloc(64 * 512 * 2);
  unsigned short* Wqhi  = (unsigned short*)alloc(64 * 512 * 2);
  unsigned short* Wqlo  = (unsigned short*)alloc(64 * 512 * 2);
  unsigned short* Wvhi  = (unsigned short*)alloc(512 * 512 * 2);
  unsigned short* Wvlo  = (unsigned short*)alloc(512 * 512 * 2);
  unsigned short* kxThi = (unsigned short*)alloc(4096 * 64 * 2);
  unsigned short* kxTlo = (unsigned short*)alloc(4096 * 64 * 2);
  unsigned short* qxThi = (unsigned short*)alloc(4096 * 64 * 2);
  unsigned short* qxTlo = (unsigned short*)alloc(4096 * 64 * 2);
  unsigned short* vbf   = (unsigned short*)alloc(512ull * 4096 * 2);
  (void)ws_size; (void)in_sizes; (void)n_in; (void)out_size;

  hipLaunchKernelGGL(xsplit_kernel, dim3(8, 64), dim3(256), 0, stream, x, xThi, xTlo);
  hipLaunchKernelGGL(wsplit_kernel, dim3(32), dim3(256), 0, stream, Wk, Wkhi, Wklo, 64 * 512 / 4);
  hipLaunchKernelGGL(wsplit_kernel, dim3(32), dim3(256), 0, stream, Wq, Wqhi, Wqlo, 64 * 512 / 4);
  hipLaunchKernelGGL(wsplit_kernel, dim3(256), dim3(256), 0, stream, Wv, Wvhi, Wvlo, 512 * 512 / 4);
  hipLaunchKernelGGL(kqproj_kernel, dim3(64, 8), dim3(256), 0, stream,
                     Wkhi, Wklo, Wqhi, Wqlo, xThi, xTlo, kxThi, kxTlo, qxThi, qxTlo);
  hipLaunchKernelGGL(vproj_kernel, dim3(256, 8), dim3(256), 0, stream, Wvhi, Wvlo, xThi, xTlo, vbf);
  hipLaunchKernelGGL(attn_kernel, dim3(256), dim3(256), 0, stream,
                     kxThi, kxTlo, qxThi, qxTlo, vbf, out);
}

// Round 2
// 303.250 us; speedup vs baseline: 1.3034x; 1.3034x over previous
//
#include <hip/hip_runtime.h>
#include <hip/hip_bf16.h>

typedef __bf16 bf16x8 __attribute__((ext_vector_type(8)));
typedef float f32x4 __attribute__((ext_vector_type(4)));
typedef unsigned int u32x4 __attribute__((ext_vector_type(4)));

#define MFMA16(a, b, c) __builtin_amdgcn_mfma_f32_16x16x32_bf16((a), (b), (c), 0, 0, 0)
#define DEVI static __device__ __forceinline__

DEVI unsigned short f2bf(float f) {  // round-to-nearest-even fp32 -> bf16
  union { float f; unsigned u; } x; x.f = f;
  unsigned r = x.u + 0x7fffu + ((x.u >> 16) & 1u);
  return (unsigned short)(r >> 16);
}
DEVI float bf2f(unsigned short h) {
  union { unsigned u; float f; } x; x.u = ((unsigned)h) << 16;
  return x.f;
}
DEVI bf16x8 ldg16(const unsigned short* p) {  // 16B aligned load -> bf16x8 frag
  u32x4 t = *reinterpret_cast<const u32x4*>(p);
  return __builtin_bit_cast(bf16x8, t);
}

// ---------- kernel 1: transpose + hi/lo split: x[512][4096] -> xThi/xTlo [4096][512]
__global__ __launch_bounds__(256) void xsplit_kernel(const float* __restrict__ x,
    unsigned short* __restrict__ xThi, unsigned short* __restrict__ xTlo) {
  __shared__ unsigned short hs[64][72];
  __shared__ unsigned short ls[64][72];
  const int c0 = blockIdx.x * 64, j0 = blockIdx.y * 64;
  const int t = threadIdx.x;
  {
    const int cr = t >> 2, jc = (t & 3) * 16;
    const float4* s4 = reinterpret_cast<const float4*>(x + (c0 + cr) * 4096 + j0 + jc);
#pragma unroll
    for (int q = 0; q < 4; ++q) {
      float4 v = s4[q];
      float vv[4] = {v.x, v.y, v.z, v.w};
#pragma unroll
      for (int e = 0; e < 4; ++e) {
        unsigned short h = f2bf(vv[e]);
        hs[cr][jc + q * 4 + e] = h;
        ls[cr][jc + q * 4 + e] = f2bf(vv[e] - bf2f(h));
      }
    }
  }
  __syncthreads();
  {
    const int jr = t >> 2, cc = (t & 3) * 16;
    unsigned short hb[16] __attribute__((aligned(16)));
    unsigned short lb[16] __attribute__((aligned(16)));
#pragma unroll
    for (int u = 0; u < 16; ++u) { hb[u] = hs[cc + u][jr]; lb[u] = ls[cc + u][jr]; }
    unsigned short* dh = xThi + (j0 + jr) * 512 + c0 + cc;
    unsigned short* dl = xTlo + (j0 + jr) * 512 + c0 + cc;
    reinterpret_cast<u32x4*>(dh)[0] = reinterpret_cast<const u32x4*>(hb)[0];
    reinterpret_cast<u32x4*>(dh)[1] = reinterpret_cast<const u32x4*>(hb)[1];
    reinterpret_cast<u32x4*>(dl)[0] = reinterpret_cast<const u32x4*>(lb)[0];
    reinterpret_cast<u32x4*>(dl)[1] = reinterpret_cast<const u32x4*>(lb)[1];
  }
}

// ---------- kernel 2: elementwise hi/lo split for all three weight matrices (one launch)
__global__ __launch_bounds__(256) void wsplit_all_kernel(
    const float* __restrict__ Wk, const float* __restrict__ Wq, const float* __restrict__ Wv,
    unsigned short* __restrict__ Wkhi, unsigned short* __restrict__ Wklo,
    unsigned short* __restrict__ Wqhi, unsigned short* __restrict__ Wqlo,
    unsigned short* __restrict__ Wvhi, unsigned short* __restrict__ Wvlo) {
  const int nk = 64 * 512 / 4, nv = 512 * 512 / 4;
  int i = blockIdx.x * 256 + threadIdx.x;
  const float* in; unsigned short* hi; unsigned short* lo; int idx;
  if (i < nk)            { in = Wk; hi = Wkhi; lo = Wklo; idx = i; }
  else if (i < 2 * nk)   { in = Wq; hi = Wqhi; lo = Wqlo; idx = i - nk; }
  else if (i < 2 * nk + nv) { in = Wv; hi = Wvhi; lo = Wvlo; idx = i - 2 * nk; }
  else return;
  float4 v = reinterpret_cast<const float4*>(in)[idx];
  float vv[4] = {v.x, v.y, v.z, v.w};
  unsigned short hb[4] __attribute__((aligned(8)));
  unsigned short lb[4] __attribute__((aligned(8)));
#pragma unroll
  for (int e = 0; e < 4; ++e) { hb[e] = f2bf(vv[e]); lb[e] = f2bf(vv[e] - bf2f(hb[e])); }
  reinterpret_cast<uint2*>(hi)[idx] = *reinterpret_cast<const uint2*>(hb);
  reinterpret_cast<uint2*>(lo)[idx] = *reinterpret_cast<const uint2*>(lb);
}

// ---------- kernel 3: kx/qx projections (split-bf16 MFMA, fp32-accurate)
__global__ __launch_bounds__(256) void kqproj_kernel(
    const unsigned short* __restrict__ Wkhi, const unsigned short* __restrict__ Wklo,
    const unsigned short* __restrict__ Wqhi, const unsigned short* __restrict__ Wqlo,
    const unsigned short* __restrict__ xThi, const unsigned short* __restrict__ xTlo,
    unsigned short* __restrict__ kxThi, unsigned short* __restrict__ kxTlo,
    unsigned short* __restrict__ qxThi, unsigned short* __restrict__ qxTlo) {
  const int mb = blockIdx.y;                       // 0..3 -> kx, 4..7 -> qx
  const int w = threadIdx.x >> 6, lane = threadIdx.x & 63;
  const int li = lane & 15, g = lane >> 4;
  const int j0 = blockIdx.x * 64 + w * 16;
  const unsigned short* Whi = (mb < 4 ? Wkhi : Wqhi) + ((mb & 3) * 16 + li) * 512 + g * 8;
  const unsigned short* Wlo = (mb < 4 ? Wklo : Wqlo) + ((mb & 3) * 16 + li) * 512 + g * 8;
  const unsigned short* Xh = xThi + (j0 + li) * 512 + g * 8;
  const unsigned short* Xl = xTlo + (j0 + li) * 512 + g * 8;
  f32x4 acc = f32x4{0.f, 0.f, 0.f, 0.f};
  for (int kf = 0; kf < 16; ++kf) {
    const int o = kf * 32;
    bf16x8 ah = ldg16(Whi + o), al = ldg16(Wlo + o);
    bf16x8 bh = ldg16(Xh + o), bl = ldg16(Xl + o);
    acc = MFMA16(ah, bh, acc);
    acc = MFMA16(ah, bl, acc);
    acc = MFMA16(al, bh, acc);
  }
  unsigned short hv[4] __attribute__((aligned(8))), lv[4] __attribute__((aligned(8)));
#pragma unroll
  for (int r = 0; r < 4; ++r) {
    hv[r] = f2bf(acc[r]);
    lv[r] = f2bf(acc[r] - bf2f(hv[r]));
  }
  unsigned short* oh = (mb < 4 ? kxThi : qxThi) + (j0 + li) * 64 + (mb & 3) * 16 + g * 4;
  unsigned short* ol = (mb < 4 ? kxTlo : qxTlo) + (j0 + li) * 64 + (mb & 3) * 16 + g * 4;
  *reinterpret_cast<uint2*>(oh) = *reinterpret_cast<const uint2*>(hv);
  *reinterpret_cast<uint2*>(ol) = *reinterpret_cast<const uint2*>(lv);
}

// ---------- kernel 4: vx projection, computed transposed -> vbf[c][j] ([512][4096] bf16)
__global__ __launch_bounds__(256) void vproj_kernel(
    const unsigned short* __restrict__ Wvhi, const unsigned short* __restrict__ Wvlo,
    const unsigned short* __restrict__ xThi, const unsigned short* __restrict__ xTlo,
    unsigned short* __restrict__ vbf) {
  const int jb = blockIdx.x, cb = blockIdx.y;
  const int w = threadIdx.x >> 6, lane = threadIdx.x & 63;
  const int li = lane & 15, g = lane >> 4;
  const int j0 = jb * 16;
  const int c0 = cb * 64 + w * 16;
  const unsigned short* Ah = xThi + (j0 + li) * 512 + g * 8;
  const unsigned short* Al = xTlo + (j0 + li) * 512 + g * 8;
  const unsigned short* Bh = Wvhi + (c0 + li) * 512 + g * 8;
  const unsigned short* Bl = Wvlo + (c0 + li) * 512 + g * 8;
  f32x4 acc = f32x4{0.f, 0.f, 0.f, 0.f};
  for (int kf = 0; kf < 16; ++kf) {
    const int o = kf * 32;
    bf16x8 ah = ldg16(Ah + o), al = ldg16(Al + o);
    bf16x8 bh = ldg16(Bh + o), bl = ldg16(Bl + o);
    acc = MFMA16(ah, bh, acc);
    acc = MFMA16(ah, bl, acc);
    acc = MFMA16(al, bh, acc);
  }
  unsigned short hv[4] __attribute__((aligned(8)));
#pragma unroll
  for (int r = 0; r < 4; ++r) hv[r] = f2bf(acc[r]);
  *reinterpret_cast<uint2*>(vbf + (c0 + li) * 4096 + j0 + g * 4) = *reinterpret_cast<const uint2*>(hv);
}

// ---------- kernel 5: flash attention, split-KV. block = 4 waves, 16 query rows,
// j-chunk = 4096/split. Writes unnormalized bf16 partial acc + f32 (m,l).
__global__ __launch_bounds__(256) void attn_kernel(
    const unsigned short* __restrict__ kxThi, const unsigned short* __restrict__ kxTlo,
    const unsigned short* __restrict__ qxThi, const unsigned short* __restrict__ qxTlo,
    const unsigned short* __restrict__ vbf,
    unsigned short* __restrict__ pacc, float* __restrict__ pml, int jchunk) {
  __shared__ __align__(16) unsigned short Pl[1024];  // 16 x 64 bf16, XOR-swizzled
  __shared__ float smax[4][16];
  __shared__ float ssum[4][16];
  const int w = threadIdx.x >> 6, lane = threadIdx.x & 63;
  const int li = lane & 15, g = lane >> 4;
  const int i0 = blockIdx.x * 16;
  const int s = blockIdx.y;
  const int jbase = s * jchunk;
  const float L2E = 1.4426950408889634f;

  bf16x8 qbh[2], qbl[2];
  {
    const unsigned short* ph = kxThi + (i0 + li) * 64 + g * 8;
    const unsigned short* pl = kxTlo + (i0 + li) * 64 + g * 8;
    qbh[0] = ldg16(ph); qbh[1] = ldg16(ph + 32);
    qbl[0] = ldg16(pl); qbl[1] = ldg16(pl + 32);
  }
  f32x4 acc[8];
#pragma unroll
  for (int cf = 0; cf < 8; ++cf) acc[cf] = f32x4{0.f, 0.f, 0.f, 0.f};
  float m_run = -3.0e38f, l_run = 0.f;
  char* plb = reinterpret_cast<char*>(Pl);

  for (int jj = 0; jj < jchunk; jj += 64) {
    const int j0 = jbase + jj;
    // --- S^T quadrant (3-term split product)
    f32x4 sc = f32x4{0.f, 0.f, 0.f, 0.f};
    {
      const unsigned short* ah_p = qxThi + (j0 + w * 16 + li) * 64 + g * 8;
      const unsigned short* al_p = qxTlo + (j0 + w * 16 + li) * 64 + g * 8;
#pragma unroll
      for (int kf = 0; kf < 2; ++kf) {
        bf16x8 ah = ldg16(ah_p + kf * 32);
        bf16x8 al = ldg16(al_p + kf * 32);
        sc = MFMA16(ah, qbh[kf], sc);
        sc = MFMA16(ah, qbl[kf], sc);
        sc = MFMA16(al, qbh[kf], sc);
      }
    }
    float pm = fmaxf(fmaxf(sc[0], sc[1]), fmaxf(sc[2], sc[3]));
    pm = fmaxf(pm, __shfl_xor(pm, 16));
    pm = fmaxf(pm, __shfl_xor(pm, 32));
    if (lane < 16) smax[w][li] = pm;
    __syncthreads();  // B1
    const float m_new = fmaxf(m_run,
        fmaxf(fmaxf(smax[0][li], smax[1][li]), fmaxf(smax[2][li], smax[3][li])));
    const float fac = exp2f((m_run - m_new) * L2E);
    float p[4];
#pragma unroll
    for (int r = 0; r < 4; ++r) p[r] = exp2f((sc[r] - m_new) * L2E);
    float ps = (p[0] + p[1]) + (p[2] + p[3]);
    ps += __shfl_xor(ps, 16);
    ps += __shfl_xor(ps, 32);
    if (lane < 16) ssum[w][li] = ps;
    {
      unsigned short pv[4] __attribute__((aligned(8)));
#pragma unroll
      for (int r = 0; r < 4; ++r) pv[r] = f2bf(p[r]);
      const int pb = (li * 128 + w * 32 + g * 8) ^ ((li & 7) << 4);
      *reinterpret_cast<uint2*>(plb + pb) = *reinterpret_cast<const uint2*>(pv);
    }
    __syncthreads();  // B2
    l_run = l_run * fac + ((ssum[0][li] + ssum[1][li]) + (ssum[2][li] + ssum[3][li]));
    m_run = m_new;
#pragma unroll
    for (int cf = 0; cf < 8; ++cf) {
#pragma unroll
      for (int r = 0; r < 4; ++r) acc[cf][r] *= fac;
    }
    bf16x8 bp[2];
#pragma unroll
    for (int kf = 0; kf < 2; ++kf) {
      const int rb = (li * 128 + kf * 64 + g * 16) ^ ((li & 7) << 4);
      bp[kf] = __builtin_bit_cast(bf16x8, *reinterpret_cast<const u32x4*>(plb + rb));
    }
#pragma unroll
    for (int cf = 0; cf < 8; ++cf) {
      const unsigned short* vp = vbf + (w * 128 + cf * 16 + li) * 4096 + j0 + g * 8;
      acc[cf] = MFMA16(ldg16(vp), bp[0], acc[cf]);
      acc[cf] = MFMA16(ldg16(vp + 32), bp[1], acc[cf]);
    }
    // (no 3rd barrier: next iter's smax/P writes are gated by B1/B2 of iter k+1)
  }
  // epilogue: unnormalized bf16 partials + per-row (m, l)
#pragma unroll
  for (int cf = 0; cf < 8; ++cf) {
    unsigned short hv[4] __attribute__((aligned(8)));
#pragma unroll
    for (int r = 0; r < 4; ++r) hv[r] = f2bf(acc[cf][r]);
    unsigned short* dp = pacc + ((size_t)(s * 4096 + i0 + li)) * 512 + w * 128 + cf * 16 + g * 4;
    *reinterpret_cast<uint2*>(dp) = *reinterpret_cast<const uint2*>(hv);
  }
  if (threadIdx.x < 16) {
    pml[((size_t)(s * 4096 + i0 + threadIdx.x)) * 2] = m_run;
    pml[((size_t)(s * 4096 + i0 + threadIdx.x)) * 2 + 1] = l_run;
  }
}

// ---------- kernel 6: combine split partials -> out [4096][512] f32
__global__ __launch_bounds__(256) void combine_kernel(
    const unsigned short* __restrict__ pacc, const float* __restrict__ pml,
    float* __restrict__ out, int split) {
  const int t = blockIdx.x * 256 + threadIdx.x;   // 4096 * 64 threads
  const int i = t >> 6, c8 = (t & 63) << 3;
  const float L2E = 1.4426950408889634f;
  float M = -3.0e38f;
  for (int ss = 0; ss < split; ++ss) M = fmaxf(M, pml[((size_t)ss * 4096 + i) * 2]);
  float num[8];
#pragma unroll
  for (int e = 0; e < 8; ++e) num[e] = 0.f;
  float den = 0.f;
  for (int ss = 0; ss < split; ++ss) {
    const float m = pml[((size_t)ss * 4096 + i) * 2];
    const float l = pml[((size_t)ss * 4096 + i) * 2 + 1];
    const float wgt = exp2f((m - M) * L2E);
    den += wgt * l;
    u32x4 pk = *reinterpret_cast<const u32x4*>(pacc + ((size_t)ss * 4096 + i) * 512 + c8);
#pragma unroll
    for (int e = 0; e < 8; ++e) {
      unsigned short h = (unsigned short)((pk[e >> 1] >> ((e & 1) * 16)) & 0xffffu);
      num[e] += wgt * bf2f(h);
    }
  }
  const float inv = 1.0f / den;
  float4 o0, o1;
  o0.x = num[0] * inv; o0.y = num[1] * inv; o0.z = num[2] * inv; o0.w = num[3] * inv;
  o1.x = num[4] * inv; o1.y = num[5] * inv; o1.z = num[6] * inv; o1.w = num[7] * inv;
  float* op = out + (size_t)i * 512 + c8;
  *reinterpret_cast<float4*>(op) = o0;
  *reinterpret_cast<float4*>(op + 4) = o1;
}

extern "C" void kernel_launch(void* const* d_in, const int* in_sizes, int n_in,
                              void* d_out, int out_size, void* d_ws, size_t ws_size,
                              hipStream_t stream) {
  const float* x  = (const float*)d_in[0];   // [512][4096]
  const float* Wk = (const float*)d_in[1];   // [64][512]
  const float* Wq = (const float*)d_in[2];   // [64][512]
  const float* Wv = (const float*)d_in[3];   // [512][512]
  float* out = (float*)d_out;                // [4096][512]
  char* ws = (char*)d_ws;

  // --- split-KV factor chosen by available workspace
  const size_t MB = 1024ull * 1024ull;
  const size_t pers_b = 2 * MB /*kx,qx hi/lo*/ + 4 * MB /*vbf*/;
  int split = 8;
  {
    size_t need8 = (size_t)8 * 4 * MB + 8 * 4096 * 8 + pers_b;   // ~38.3 MB
    if (ws_size < need8) split = 4;                               // ~22.2 MB
  }
  const size_t pacc_b = (size_t)split * 4 * MB;
  const size_t pml_b  = (size_t)split * 4096 * 8;

  // persistent region (live during attn): after partials
  char* pers = ws + pacc_b + pml_b;
  unsigned short* pacc  = (unsigned short*)ws;
  float*          pml   = (float*)(ws + pacc_b);
  unsigned short* kxThi = (unsigned short*)(pers + 0 * 512 * 1024);
  unsigned short* kxTlo = (unsigned short*)(pers + 1 * 512 * 1024);
  unsigned short* qxThi = (unsigned short*)(pers + 2 * 512 * 1024);
  unsigned short* qxTlo = (unsigned short*)(pers + 3 * 512 * 1024);
  unsigned short* vbf   = (unsigned short*)(pers + 4 * 512 * 1024);
  // temporaries (dead before attn) overlay the partial-acc region (pacc_b >= 9.7MB)
  unsigned short* xThi = (unsigned short*)(ws + 0 * MB);
  unsigned short* xTlo = (unsigned short*)(ws + 4 * MB);
  char* wbase = ws + 8 * MB;
  unsigned short* Wkhi = (unsigned short*)(wbase + 0 * 64 * 1024);
  unsigned short* Wklo = (unsigned short*)(wbase + 1 * 64 * 1024);
  unsigned short* Wqhi = (unsigned short*)(wbase + 2 * 64 * 1024);
  unsigned short* Wqlo = (unsigned short*)(wbase + 3 * 64 * 1024);
  unsigned short* Wvhi = (unsigned short*)(wbase + 4 * 64 * 1024);
  unsigned short* Wvlo = (unsigned short*)(wbase + 12 * 64 * 1024);
  (void)in_sizes; (void)n_in; (void)out_size;

  hipLaunchKernelGGL(xsplit_kernel, dim3(8, 64), dim3(256), 0, stream, x, xThi, xTlo);
  hipLaunchKernelGGL(wsplit_all_kernel, dim3(320), dim3(256), 0, stream,
                     Wk, Wq, Wv, Wkhi, Wklo, Wqhi, Wqlo, Wvhi, Wvlo);
  hipLaunchKernelGGL(kqproj_kernel, dim3(64, 8), dim3(256), 0, stream,
                     Wkhi, Wklo, Wqhi, Wqlo, xThi, xTlo, kxThi, kxTlo, qxThi, qxTlo);
  hipLaunchKernelGGL(vproj_kernel, dim3(256, 8), dim3(256), 0, stream, Wvhi, Wvlo, xThi, xTlo, vbf);
  hipLaunchKernelGGL(attn_kernel, dim3(256, split), dim3(256), 0, stream,
                     kxThi, kxTlo, qxThi, qxTlo, vbf, pacc, pml, 4096 / split);
  hipLaunchKernelGGL(combine_kernel, dim3(1024), dim3(256), 0, stream, pacc, pml, out, split);
}

// Round 3
// 175.648 us; speedup vs baseline: 2.2503x; 1.7265x over previous
//
#include <hip/hip_runtime.h>
#include <hip/hip_bf16.h>

typedef __bf16 bf16x8 __attribute__((ext_vector_type(8)));
typedef float f32x4 __attribute__((ext_vector_type(4)));
typedef unsigned int u32x4 __attribute__((ext_vector_type(4)));

#define MFMA16(a, b, c) __builtin_amdgcn_mfma_f32_16x16x32_bf16((a), (b), (c), 0, 0, 0)
#define DEVI static __device__ __forceinline__

DEVI unsigned short f2bf(float f) {  // round-to-nearest-even fp32 -> bf16
  union { float f; unsigned u; } x; x.f = f;
  unsigned r = x.u + 0x7fffu + ((x.u >> 16) & 1u);
  return (unsigned short)(r >> 16);
}
DEVI float bf2f(unsigned short h) {
  union { unsigned u; float f; } x; x.u = ((unsigned)h) << 16;
  return x.f;
}
DEVI bf16x8 ld16(const void* p) {  // 16B aligned load (global or LDS) -> bf16x8
  u32x4 t = *reinterpret_cast<const u32x4*>(p);
  return __builtin_bit_cast(bf16x8, t);
}

// ---------- kernel 1: transpose + hi/lo split: x[512][4096] -> xThi/xTlo [4096][512]
__global__ __launch_bounds__(256) void xsplit_kernel(const float* __restrict__ x,
    unsigned short* __restrict__ xThi, unsigned short* __restrict__ xTlo) {
  __shared__ unsigned short hs[64][72];
  __shared__ unsigned short ls[64][72];
  const int c0 = blockIdx.x * 64, j0 = blockIdx.y * 64;
  const int t = threadIdx.x;
  {
    const int cr = t >> 2, jc = (t & 3) * 16;
    const float4* s4 = reinterpret_cast<const float4*>(x + (c0 + cr) * 4096 + j0 + jc);
#pragma unroll
    for (int q = 0; q < 4; ++q) {
      float4 v = s4[q];
      float vv[4] = {v.x, v.y, v.z, v.w};
#pragma unroll
      for (int e = 0; e < 4; ++e) {
        unsigned short h = f2bf(vv[e]);
        hs[cr][jc + q * 4 + e] = h;
        ls[cr][jc + q * 4 + e] = f2bf(vv[e] - bf2f(h));
      }
    }
  }
  __syncthreads();
  {
    const int jr = t >> 2, cc = (t & 3) * 16;
    unsigned short hb[16] __attribute__((aligned(16)));
    unsigned short lb[16] __attribute__((aligned(16)));
#pragma unroll
    for (int u = 0; u < 16; ++u) { hb[u] = hs[cc + u][jr]; lb[u] = ls[cc + u][jr]; }
    unsigned short* dh = xThi + (j0 + jr) * 512 + c0 + cc;
    unsigned short* dl = xTlo + (j0 + jr) * 512 + c0 + cc;
    reinterpret_cast<u32x4*>(dh)[0] = reinterpret_cast<const u32x4*>(hb)[0];
    reinterpret_cast<u32x4*>(dh)[1] = reinterpret_cast<const u32x4*>(hb)[1];
    reinterpret_cast<u32x4*>(dl)[0] = reinterpret_cast<const u32x4*>(lb)[0];
    reinterpret_cast<u32x4*>(dl)[1] = reinterpret_cast<const u32x4*>(lb)[1];
  }
}

// ---------- kernel 2: elementwise hi/lo split for all three weight matrices
__global__ __launch_bounds__(256) void wsplit_all_kernel(
    const float* __restrict__ Wk, const float* __restrict__ Wq, const float* __restrict__ Wv,
    unsigned short* __restrict__ Wkhi, unsigned short* __restrict__ Wklo,
    unsigned short* __restrict__ Wqhi, unsigned short* __restrict__ Wqlo,
    unsigned short* __restrict__ Wvhi, unsigned short* __restrict__ Wvlo) {
  const int nk = 64 * 512 / 4, nv = 512 * 512 / 4;
  int i = blockIdx.x * 256 + threadIdx.x;
  const float* in; unsigned short* hi; unsigned short* lo; int idx;
  if (i < nk)            { in = Wk; hi = Wkhi; lo = Wklo; idx = i; }
  else if (i < 2 * nk)   { in = Wq; hi = Wqhi; lo = Wqlo; idx = i - nk; }
  else if (i < 2 * nk + nv) { in = Wv; hi = Wvhi; lo = Wvlo; idx = i - 2 * nk; }
  else return;
  float4 v = reinterpret_cast<const float4*>(in)[idx];
  float vv[4] = {v.x, v.y, v.z, v.w};
  unsigned short hb[4] __attribute__((aligned(8)));
  unsigned short lb[4] __attribute__((aligned(8)));
#pragma unroll
  for (int e = 0; e < 4; ++e) { hb[e] = f2bf(vv[e]); lb[e] = f2bf(vv[e] - bf2f(hb[e])); }
  reinterpret_cast<uint2*>(hi)[idx] = *reinterpret_cast<const uint2*>(hb);
  reinterpret_cast<uint2*>(lo)[idx] = *reinterpret_cast<const uint2*>(lb);
}

// ---------- kernel 3: kx/qx projections (split-bf16 MFMA, fp32-accurate)
__global__ __launch_bounds__(256) void kqproj_kernel(
    const unsigned short* __restrict__ Wkhi, const unsigned short* __restrict__ Wklo,
    const unsigned short* __restrict__ Wqhi, const unsigned short* __restrict__ Wqlo,
    const unsigned short* __restrict__ xThi, const unsigned short* __restrict__ xTlo,
    unsigned short* __restrict__ kxThi, unsigned short* __restrict__ kxTlo,
    unsigned short* __restrict__ qxThi, unsigned short* __restrict__ qxTlo) {
  const int mb = blockIdx.y;                       // 0..3 -> kx, 4..7 -> qx
  const int w = threadIdx.x >> 6, lane = threadIdx.x & 63;
  const int li = lane & 15, g = lane >> 4;
  const int j0 = blockIdx.x * 64 + w * 16;
  const unsigned short* Whi = (mb < 4 ? Wkhi : Wqhi) + ((mb & 3) * 16 + li) * 512 + g * 8;
  const unsigned short* Wlo = (mb < 4 ? Wklo : Wqlo) + ((mb & 3) * 16 + li) * 512 + g * 8;
  const unsigned short* Xh = xThi + (j0 + li) * 512 + g * 8;
  const unsigned short* Xl = xTlo + (j0 + li) * 512 + g * 8;
  f32x4 acc = f32x4{0.f, 0.f, 0.f, 0.f};
  for (int kf = 0; kf < 16; ++kf) {
    const int o = kf * 32;
    bf16x8 ah = ld16(Whi + o), al = ld16(Wlo + o);
    bf16x8 bh = ld16(Xh + o), bl = ld16(Xl + o);
    acc = MFMA16(ah, bh, acc);
    acc = MFMA16(ah, bl, acc);
    acc = MFMA16(al, bh, acc);
  }
  unsigned short hv[4] __attribute__((aligned(8))), lv[4] __attribute__((aligned(8)));
#pragma unroll
  for (int r = 0; r < 4; ++r) {
    hv[r] = f2bf(acc[r]);
    lv[r] = f2bf(acc[r] - bf2f(hv[r]));
  }
  unsigned short* oh = (mb < 4 ? kxThi : qxThi) + (j0 + li) * 64 + (mb & 3) * 16 + g * 4;
  unsigned short* ol = (mb < 4 ? kxTlo : qxTlo) + (j0 + li) * 64 + (mb & 3) * 16 + g * 4;
  *reinterpret_cast<uint2*>(oh) = *reinterpret_cast<const uint2*>(hv);
  *reinterpret_cast<uint2*>(ol) = *reinterpret_cast<const uint2*>(lv);
}

// ---------- kernel 4: vx projection, transposed output vbf[c][j] ([512][4096] bf16)
// retiled: wave computes 32j x 32c, block (4 waves) = 64j x 64c
__global__ __launch_bounds__(256) void vproj_kernel(
    const unsigned short* __restrict__ Wvhi, const unsigned short* __restrict__ Wvlo,
    const unsigned short* __restrict__ xThi, const unsigned short* __restrict__ xTlo,
    unsigned short* __restrict__ vbf) {
  const int w = threadIdx.x >> 6, lane = threadIdx.x & 63;
  const int li = lane & 15, g = lane >> 4;
  const int j0 = blockIdx.x * 64 + (w >> 1) * 32;
  const int c0 = blockIdx.y * 64 + (w & 1) * 32;
  f32x4 acc[2][2];
#pragma unroll
  for (int mf = 0; mf < 2; ++mf)
#pragma unroll
    for (int nf = 0; nf < 2; ++nf) acc[mf][nf] = f32x4{0.f, 0.f, 0.f, 0.f};
  for (int kf = 0; kf < 16; ++kf) {
    const int kk = kf * 32 + g * 8;
    bf16x8 ah[2], al[2], bh[2], bl[2];
#pragma unroll
    for (int mf = 0; mf < 2; ++mf) {
      ah[mf] = ld16(xThi + (j0 + mf * 16 + li) * 512 + kk);
      al[mf] = ld16(xTlo + (j0 + mf * 16 + li) * 512 + kk);
    }
#pragma unroll
    for (int nf = 0; nf < 2; ++nf) {
      bh[nf] = ld16(Wvhi + (c0 + nf * 16 + li) * 512 + kk);
      bl[nf] = ld16(Wvlo + (c0 + nf * 16 + li) * 512 + kk);
    }
#pragma unroll
    for (int mf = 0; mf < 2; ++mf)
#pragma unroll
      for (int nf = 0; nf < 2; ++nf) {
        acc[mf][nf] = MFMA16(ah[mf], bh[nf], acc[mf][nf]);
        acc[mf][nf] = MFMA16(ah[mf], bl[nf], acc[mf][nf]);
        acc[mf][nf] = MFMA16(al[mf], bh[nf], acc[mf][nf]);
      }
  }
#pragma unroll
  for (int mf = 0; mf < 2; ++mf)
#pragma unroll
    for (int nf = 0; nf < 2; ++nf) {
      unsigned short hv[4] __attribute__((aligned(8)));
#pragma unroll
      for (int r = 0; r < 4; ++r) hv[r] = f2bf(acc[mf][nf][r]);
      *reinterpret_cast<uint2*>(vbf + (size_t)(c0 + nf * 16 + li) * 4096 + j0 + mf * 16 + g * 4) =
          *reinterpret_cast<const uint2*>(hv);
    }
}

// ---------- kernel 5: flash attention, split-KV, QBLK=64.
// block = 4 waves, 64 query rows; Q staged in swizzled LDS (shared by waves);
// wave w: S^T j-quadrant [w*16,w*16+16) x 64 i; P = 64x64 swizzled LDS;
// PV channel-split: wave w accumulates channels [w*128,(w+1)*128) x 64 i.
__global__ __launch_bounds__(256, 2) void attn_kernel(
    const unsigned short* __restrict__ kxThi, const unsigned short* __restrict__ kxTlo,
    const unsigned short* __restrict__ qxThi, const unsigned short* __restrict__ qxTlo,
    const unsigned short* __restrict__ vbf,
    unsigned short* __restrict__ pacc, float* __restrict__ pml, int split) {
  __shared__ __align__(16) unsigned short QLh[4096];  // 64x64 bf16, swizzled
  __shared__ __align__(16) unsigned short QLl[4096];
  __shared__ __align__(16) unsigned short PL[4096];   // 64x64 bf16, swizzled
  __shared__ __align__(16) float smax[64][4];
  __shared__ __align__(16) float ssum[64][4];
  const int jchunk = 4096 / split;
  const int s = blockIdx.x % split;            // XCD-affine j-chunk (wgid%8 = XCD)
  const int i0 = (blockIdx.x / split) * 64;
  const int jbase = s * jchunk;
  const int w = threadIdx.x >> 6, lane = threadIdx.x & 63;
  const int li = lane & 15, g = lane >> 4;
  const float L2E = 1.4426950408889634f;
  char* qlh = reinterpret_cast<char*>(QLh);
  char* qll = reinterpret_cast<char*>(QLl);
  char* plb = reinterpret_cast<char*>(PL);

  // cooperative Q stage (kx^T rows i0..i0+63 hi/lo), swizzle ^((row&7)<<4)
  {
    const int qi = threadIdx.x >> 2;
#pragma unroll
    for (int cc = 0; cc < 2; ++cc) {
      const int ch = (threadIdx.x & 3) + cc * 4;        // 16B chunk 0..7
      const int src = (i0 + qi) * 64 + ch * 8;
      const int dst = (qi * 128 + ch * 16) ^ ((qi & 7) << 4);
      *reinterpret_cast<u32x4*>(qlh + dst) = *reinterpret_cast<const u32x4*>(kxThi + src);
      *reinterpret_cast<u32x4*>(qll + dst) = *reinterpret_cast<const u32x4*>(kxTlo + src);
    }
  }
  f32x4 acc[8][4];  // [cf][if]
#pragma unroll
  for (int cf = 0; cf < 8; ++cf)
#pragma unroll
    for (int f = 0; f < 4; ++f) acc[cf][f] = f32x4{0.f, 0.f, 0.f, 0.f};
  float m_run[4] = {-3.0e38f, -3.0e38f, -3.0e38f, -3.0e38f};
  float l_run[4] = {0.f, 0.f, 0.f, 0.f};
  __syncthreads();  // Q stage visible

  for (int jj = 0; jj < jchunk; jj += 64) {
    const int j0 = jbase + jj;
    // --- S^T quadrant: rows j = j0 + w*16 + (g*4+r), cols i = f*16+li (3-term split)
    f32x4 sc[4];
#pragma unroll
    for (int f = 0; f < 4; ++f) sc[f] = f32x4{0.f, 0.f, 0.f, 0.f};
    {
      const unsigned short* ah_p = qxThi + (j0 + w * 16 + li) * 64 + g * 8;
      const unsigned short* al_p = qxTlo + (j0 + w * 16 + li) * 64 + g * 8;
#pragma unroll
      for (int kf = 0; kf < 2; ++kf) {
        bf16x8 ah = ld16(ah_p + kf * 32);
        bf16x8 al = ld16(al_p + kf * 32);
#pragma unroll
        for (int f = 0; f < 4; ++f) {
          const int qb = ((f * 16 + li) * 128 + kf * 64 + g * 16) ^ ((li & 7) << 4);
          bf16x8 qh = ld16(qlh + qb);
          bf16x8 ql = ld16(qll + qb);
          sc[f] = MFMA16(ah, qh, sc[f]);
          sc[f] = MFMA16(ah, ql, sc[f]);
          sc[f] = MFMA16(al, qh, sc[f]);
        }
      }
    }
    // --- per-column quadrant max -> smax[i][w]
    {
      float pm[4];
#pragma unroll
      for (int f = 0; f < 4; ++f) {
        float t = fmaxf(fmaxf(sc[f][0], sc[f][1]), fmaxf(sc[f][2], sc[f][3]));
        t = fmaxf(t, __shfl_xor(t, 16));
        t = fmaxf(t, __shfl_xor(t, 32));
        pm[f] = t;
      }
      if (lane < 16) {
#pragma unroll
        for (int f = 0; f < 4; ++f) smax[f * 16 + li][w] = pm[f];
      }
    }
    __syncthreads();  // B1
    float m_new[4], fac[4];
#pragma unroll
    for (int f = 0; f < 4; ++f) {
      const f32x4 sm = *reinterpret_cast<const f32x4*>(&smax[f * 16 + li][0]);
      m_new[f] = fmaxf(m_run[f], fmaxf(fmaxf(sm[0], sm[1]), fmaxf(sm[2], sm[3])));
      fac[f] = exp2f((m_run[f] - m_new[f]) * L2E);
      m_run[f] = m_new[f];
    }
#pragma unroll
    for (int f = 0; f < 4; ++f) {
      float p[4];
#pragma unroll
      for (int r = 0; r < 4; ++r) p[r] = exp2f((sc[f][r] - m_new[f]) * L2E);
      float ps = (p[0] + p[1]) + (p[2] + p[3]);
      ps += __shfl_xor(ps, 16);
      ps += __shfl_xor(ps, 32);
      if (lane < 16) ssum[f * 16 + li][w] = ps;
      unsigned short pv[4] __attribute__((aligned(8)));
#pragma unroll
      for (int r = 0; r < 4; ++r) pv[r] = f2bf(p[r]);
      const int pb = ((f * 16 + li) * 128 + w * 32 + g * 8) ^ ((li & 7) << 4);
      *reinterpret_cast<uint2*>(plb + pb) = *reinterpret_cast<const uint2*>(pv);
    }
    __syncthreads();  // B2
#pragma unroll
    for (int f = 0; f < 4; ++f) {
      const f32x4 ss = *reinterpret_cast<const f32x4*>(&ssum[f * 16 + li][0]);
      l_run[f] = l_run[f] * fac[f] + ((ss[0] + ss[1]) + (ss[2] + ss[3]));
    }
#pragma unroll
    for (int cf = 0; cf < 8; ++cf)
#pragma unroll
      for (int f = 0; f < 4; ++f) {
#pragma unroll
        for (int r = 0; r < 4; ++r) acc[cf][f][r] *= fac[f];
      }
    // --- PV: B = P frags from LDS, A = V rows (global, L2-resident)
    bf16x8 bp[4][2];
#pragma unroll
    for (int f = 0; f < 4; ++f)
#pragma unroll
      for (int kf = 0; kf < 2; ++kf) {
        const int rb = ((f * 16 + li) * 128 + kf * 64 + g * 16) ^ ((li & 7) << 4);
        bp[f][kf] = ld16(plb + rb);
      }
#pragma unroll
    for (int cf = 0; cf < 8; ++cf) {
      const unsigned short* vp = vbf + (size_t)(w * 128 + cf * 16 + li) * 4096 + j0 + g * 8;
      bf16x8 a0 = ld16(vp);
      bf16x8 a1 = ld16(vp + 32);
#pragma unroll
      for (int f = 0; f < 4; ++f) {
        acc[cf][f] = MFMA16(a0, bp[f][0], acc[cf][f]);
        acc[cf][f] = MFMA16(a1, bp[f][1], acc[cf][f]);
      }
    }
    // (2 barriers/iter suffice: smax writes sit behind B2(k-1); ssum/P writes behind B1(k))
  }
  // epilogue: unnormalized bf16 partials + per-row (m, l)
#pragma unroll
  for (int cf = 0; cf < 8; ++cf)
#pragma unroll
    for (int f = 0; f < 4; ++f) {
      unsigned short hv[4] __attribute__((aligned(8)));
#pragma unroll
      for (int r = 0; r < 4; ++r) hv[r] = f2bf(acc[cf][f][r]);
      unsigned short* dp = pacc + ((size_t)(s * 4096 + i0 + f * 16 + li)) * 512 + w * 128 + cf * 16 + g * 4;
      *reinterpret_cast<uint2*>(dp) = *reinterpret_cast<const uint2*>(hv);
    }
  if (w == 0 && lane < 16) {
#pragma unroll
    for (int f = 0; f < 4; ++f) {
      pml[((size_t)(s * 4096 + i0 + f * 16 + li)) * 2] = m_run[f];
      pml[((size_t)(s * 4096 + i0 + f * 16 + li)) * 2 + 1] = l_run[f];
    }
  }
}

// ---------- kernel 6: combine split partials -> out [4096][512] f32
__global__ __launch_bounds__(256) void combine_kernel(
    const unsigned short* __restrict__ pacc, const float* __restrict__ pml,
    float* __restrict__ out, int split) {
  const int t = blockIdx.x * 256 + threadIdx.x;   // 4096 * 64 threads
  const int i = t >> 6, c8 = (t & 63) << 3;
  const float L2E = 1.4426950408889634f;
  float M = -3.0e38f;
  for (int ss = 0; ss < split; ++ss) M = fmaxf(M, pml[((size_t)ss * 4096 + i) * 2]);
  float num[8];
#pragma unroll
  for (int e = 0; e < 8; ++e) num[e] = 0.f;
  float den = 0.f;
  for (int ss = 0; ss < split; ++ss) {
    const float m = pml[((size_t)ss * 4096 + i) * 2];
    const float l = pml[((size_t)ss * 4096 + i) * 2 + 1];
    const float wgt = exp2f((m - M) * L2E);
    den += wgt * l;
    u32x4 pk = *reinterpret_cast<const u32x4*>(pacc + ((size_t)ss * 4096 + i) * 512 + c8);
#pragma unroll
    for (int e = 0; e < 8; ++e) {
      unsigned short h = (unsigned short)((pk[e >> 1] >> ((e & 1) * 16)) & 0xffffu);
      num[e] += wgt * bf2f(h);
    }
  }
  const float inv = 1.0f / den;
  float4 o0, o1;
  o0.x = num[0] * inv; o0.y = num[1] * inv; o0.z = num[2] * inv; o0.w = num[3] * inv;
  o1.x = num[4] * inv; o1.y = num[5] * inv; o1.z = num[6] * inv; o1.w = num[7] * inv;
  float* op = out + (size_t)i * 512 + c8;
  *reinterpret_cast<float4*>(op) = o0;
  *reinterpret_cast<float4*>(op + 4) = o1;
}

extern "C" void kernel_launch(void* const* d_in, const int* in_sizes, int n_in,
                              void* d_out, int out_size, void* d_ws, size_t ws_size,
                              hipStream_t stream) {
  const float* x  = (const float*)d_in[0];   // [512][4096]
  const float* Wk = (const float*)d_in[1];   // [64][512]
  const float* Wq = (const float*)d_in[2];   // [64][512]
  const float* Wv = (const float*)d_in[3];   // [512][512]
  float* out = (float*)d_out;                // [4096][512]
  char* ws = (char*)d_ws;

  const size_t MB = 1024ull * 1024ull;
  const size_t pers_b = 2 * MB /*kx,qx hi/lo*/ + 4 * MB /*vbf*/;
  int split = 8;
  {
    size_t need8 = (size_t)8 * 4 * MB + 8 * 4096 * 8 + pers_b;   // ~38.3 MB
    if (ws_size < need8) split = 4;                               // ~22.2 MB
  }
  const size_t pacc_b = (size_t)split * 4 * MB;
  const size_t pml_b  = (size_t)split * 4096 * 8;

  // persistent region (live during attn): after partials
  char* pers = ws + pacc_b + pml_b;
  unsigned short* pacc  = (unsigned short*)ws;
  float*          pml   = (float*)(ws + pacc_b);
  unsigned short* kxThi = (unsigned short*)(pers + 0 * 512 * 1024);
  unsigned short* kxTlo = (unsigned short*)(pers + 1 * 512 * 1024);
  unsigned short* qxThi = (unsigned short*)(pers + 2 * 512 * 1024);
  unsigned short* qxTlo = (unsigned short*)(pers + 3 * 512 * 1024);
  unsigned short* vbf   = (unsigned short*)(pers + 4 * 512 * 1024);
  // temporaries (dead before attn) overlay the partial-acc region (pacc_b >= 9.7MB)
  unsigned short* xThi = (unsigned short*)(ws + 0 * MB);
  unsigned short* xTlo = (unsigned short*)(ws + 4 * MB);
  char* wbase = ws + 8 * MB;
  unsigned short* Wkhi = (unsigned short*)(wbase + 0 * 64 * 1024);
  unsigned short* Wklo = (unsigned short*)(wbase + 1 * 64 * 1024);
  unsigned short* Wqhi = (unsigned short*)(wbase + 2 * 64 * 1024);
  unsigned short* Wqlo = (unsigned short*)(wbase + 3 * 64 * 1024);
  unsigned short* Wvhi = (unsigned short*)(wbase + 4 * 64 * 1024);
  unsigned short* Wvlo = (unsigned short*)(wbase + 12 * 64 * 1024);
  (void)in_sizes; (void)n_in; (void)out_size;

  hipLaunchKernelGGL(xsplit_kernel, dim3(8, 64), dim3(256), 0, stream, x, xThi, xTlo);
  hipLaunchKernelGGL(wsplit_all_kernel, dim3(320), dim3(256), 0, stream,
                     Wk, Wq, Wv, Wkhi, Wklo, Wqhi, Wqlo, Wvhi, Wvlo);
  hipLaunchKernelGGL(kqproj_kernel, dim3(64, 8), dim3(256), 0, stream,
                     Wkhi, Wklo, Wqhi, Wqlo, xThi, xTlo, kxThi, kxTlo, qxThi, qxTlo);
  hipLaunchKernelGGL(vproj_kernel, dim3(64, 8), dim3(256), 0, stream, Wvhi, Wvlo, xThi, xTlo, vbf);
  hipLaunchKernelGGL(attn_kernel, dim3(64 * split), dim3(256), 0, stream,
                     kxThi, kxTlo, qxThi, qxTlo, vbf, pacc, pml, split);
  hipLaunchKernelGGL(combine_kernel, dim3(1024), dim3(256), 0, stream, pacc, pml, out, split);
}